// Round 13
// baseline (689.071 us; speedup 1.0000x reference)
//
#include <hip/hip_runtime.h>
#include <hip/hip_bf16.h>

#define BB 128   // batch
#define TT 512   // time
#define EE 100   // embed dim
#define HH 128   // hidden
#define KK 12    // tags
#define VV 50257 // vocab
#define NB 4     // batches per block (recurrent)
#define NBLK 32  // recurrent blocks

typedef short bf16x8 __attribute__((ext_vector_type(8)));
typedef float f32x4  __attribute__((ext_vector_type(4)));

__device__ __forceinline__ unsigned short f2bf(float x) {
  __hip_bfloat16 h = __float2bfloat16(x);
  return *reinterpret_cast<unsigned short*>(&h);
}
__device__ __forceinline__ float bf2f(unsigned short u) {
  return __uint_as_float(((unsigned)u) << 16);
}

__device__ __forceinline__ bf16x8 load8_bf(const float* p) {
  float4 a = *reinterpret_cast<const float4*>(p);
  float4 b = *reinterpret_cast<const float4*>(p + 4);
  bf16x8 r;
  r[0] = (short)f2bf(a.x); r[1] = (short)f2bf(a.y);
  r[2] = (short)f2bf(a.z); r[3] = (short)f2bf(a.w);
  r[4] = (short)f2bf(b.x); r[5] = (short)f2bf(b.y);
  r[6] = (short)f2bf(b.z); r[7] = (short)f2bf(b.w);
  return r;
}

// Wih fragment chunk with bias folded at k==EE, zeros past
__device__ __forceinline__ bf16x8 load8_bf_pad_bias(const float* row, int k0,
                                                    float bias) {
  bf16x8 r;
  #pragma unroll
  for (int i = 0; i < 8; ++i) {
    int k = k0 + i;
    unsigned short v = 0;
    if (k < EE) v = f2bf(row[k]);
    else if (k == EE) v = f2bf(bias);
    r[i] = (short)v;
  }
  return r;
}

// ushort index of (row b, col k) in A-frag-ordered tile (lane-linear)
__device__ __forceinline__ int frag_idx(int b, int k) {
  return ((k >> 5) << 9) + ((b + (((k >> 3) & 3) << 4)) << 3) + (k & 7);
}

// ---------------------------------------------------------------------------
// Kernel 0: precast embed -> bf16 [V][128]; col 100 = 1.0 (bias slot), rest 0.
// ---------------------------------------------------------------------------
__global__ __launch_bounds__(256) void precast_kernel(
    const float* __restrict__ embed, unsigned short* __restrict__ ebf)
{
  int id = blockIdx.x * 256 + threadIdx.x;
  if (id >= VV * 16) return;
  int v = id >> 4, g = id & 15;
  const float* row = embed + (size_t)v * EE;
  bf16x8 o;
  #pragma unroll
  for (int i = 0; i < 8; ++i) {
    int k = g * 8 + i;
    unsigned short u = 0;
    if (k < EE) u = f2bf(row[k]);
    else if (k == EE) u = 0x3F80;   // 1.0 bf16
    o[i] = (short)u;
  }
  *reinterpret_cast<bf16x8*>(ebf + (size_t)id * 8) = o;
}

// ---------------------------------------------------------------------------
// Kernel 1: Wih -> B-fragment table wbf[s8][tt][kt][lane] (bf16x8 each).
// ---------------------------------------------------------------------------
__global__ __launch_bounds__(256) void wprep_kernel(
    const float* __restrict__ Wih, const float* __restrict__ bih,
    const float* __restrict__ bhh, unsigned short* __restrict__ wbf)
{
  int id = blockIdx.x * 256 + threadIdx.x;   // 8192 frags
  if (id >= 8 * 4 * 4 * 64) return;
  int l = id & 63, kt = (id >> 6) & 3, tt = (id >> 8) & 3, s8 = id >> 10;
  int gcol = tt * HH + 16 * s8 + (l & 15);
  int k0 = kt * 32 + (l >> 4) * 8;
  float bias = bih[gcol] + bhh[gcol];
  bf16x8 r = load8_bf_pad_bias(Wih + (size_t)gcol * EE, k0, bias);
  *reinterpret_cast<bf16x8*>(wbf + (size_t)id * 8) = r;
}

// ---------------------------------------------------------------------------
// Kernel 2: pregates GEMM. P16[flat(b,t)][e][tt] bf16 quad-interleaved.
// ---------------------------------------------------------------------------
__global__ __launch_bounds__(256, 2) void pregates_kernel(
    const int* __restrict__ sent, const unsigned short* __restrict__ ebf,
    const unsigned short* __restrict__ wbf, unsigned short* __restrict__ P16)
{
  const int w = threadIdx.x >> 6, l = threadIdx.x & 63;
  const int c = l & 15, q = l >> 4;
  const int rt = blockIdx.x * 4 + w;
  const int flat = rt * 16 + c;               // this lane's A row
  const int b = flat >> 9, t = flat & 511;
  const int id = sent[b * TT + t];

  bf16x8 xa[4];
  #pragma unroll
  for (int kt = 0; kt < 4; ++kt)
    xa[kt] = *reinterpret_cast<const bf16x8*>(
        ebf + (size_t)id * 128 + kt * 32 + q * 8);

  const bf16x8* wb = reinterpret_cast<const bf16x8*>(wbf);
  #pragma unroll
  for (int s8 = 0; s8 < 8; ++s8) {
    f32x4 acc[4];
    #pragma unroll
    for (int tt = 0; tt < 4; ++tt) {
      f32x4 z = {0.f, 0.f, 0.f, 0.f};
      acc[tt] = z;
    }
    #pragma unroll
    for (int kt = 0; kt < 4; ++kt) {
      #pragma unroll
      for (int tt = 0; tt < 4; ++tt)
        acc[tt] = __builtin_amdgcn_mfma_f32_16x16x32_bf16(
            xa[kt], wb[((s8 * 4 + tt) * 4 + kt) * 64 + l], acc[tt], 0, 0, 0);
    }
    const int e = s8 * 16 + c;
    #pragma unroll
    for (int r4 = 0; r4 < 4; ++r4) {
      int fr = rt * 16 + q * 4 + r4;          // D row = (l>>4)*4 + reg
      ushort4 o = make_ushort4(f2bf(acc[0][r4]), f2bf(acc[1][r4]),
                               f2bf(acc[2][r4]), f2bf(acc[3][r4]));
      *reinterpret_cast<ushort4*>(P16 + ((size_t)fr * 128 + e) * 4) = o;
    }
  }
}

// ---------------------------------------------------------------------------
// Kernel 3: recurrent LSTM + emissions + Viterbi + backtrace.
// grid = 32 blocks (4 batches) x 512 threads (8 waves). Batch lb at MFMA row
// lb*4 -> ONE cell row per lane (halves quarter-rate transcendental work, the
// measured dominant term). Merged-rcp activations: 5 exp2 + 3 rcp per (b,e).
// Wave 0: emission (lag 1). Waves 4-7: Viterbi (lag 2, batch w-4).
// 60KB dynamic LDS -> ~82KB/block -> exactly 1 block/CU (no packing).
// ---------------------------------------------------------------------------
__global__ __launch_bounds__(512, 2) void lstm_crf_fused(
    const unsigned short* __restrict__ P16, const float* __restrict__ Whh,
    const float* __restrict__ h0, const float* __restrict__ c0,
    const float* __restrict__ Wtag, const float* __restrict__ btag,
    const float* __restrict__ trans, float* __restrict__ out)
{
  __shared__ unsigned char bp[256 * (NB * 12)];            // 12 KB nibble-packed
  __shared__ __align__(16) unsigned short hfrag[2][2048];  // 8 KB h, frag order
  __shared__ __align__(16) float vit[NB * 16];
  __shared__ __align__(16) float trl[KK * 16];             // trl[j*16+i]=trans[i][j]
  __shared__ __align__(16) float ering[2][NB * 16];        // emission ring
  extern __shared__ char dynpad[];                         // occupancy limiter
  (void)dynpad;

  const int bg  = blockIdx.x;
  const int tid = threadIdx.x;
  const int w   = tid >> 6;         // wave 0..7
  const int l   = tid & 63;
  const int c   = l & 15;           // MFMA col within tile
  const int q   = l >> 4;           // row group; batch q at row q*4
  const int ew  = 16 * w + c;       // this lane's gate column (e)

  // ---- weights: 4 gate-tiles {i,f,g,o} of e-strip (h-side only) ----
  bf16x8 wh[4][4];
  #pragma unroll
  for (int tt = 0; tt < 4; ++tt) {
    const int gcol = tt * HH + ew;
    #pragma unroll
    for (int kt = 0; kt < 4; ++kt)
      wh[tt][kt] = load8_bf(Whh + (size_t)gcol * HH + kt * 32 + q * 8);
  }

  // ---- cell state: lane (q,c) holds c for batch q, e=ew ----
  float cst = c0[(size_t)(bg * NB + q) * HH + ew];

  // ---- emission weight fragments (wave 0) ----
  bf16x8 we[4];
  #pragma unroll
  for (int kt = 0; kt < 4; ++kt) {
    #pragma unroll
    for (int i = 0; i < 8; ++i) we[kt][i] = 0;
  }
  float bt = 0.f;
  if (w == 0 && c < KK) {
    #pragma unroll
    for (int kt = 0; kt < 4; ++kt)
      we[kt] = load8_bf(Wtag + (size_t)c * HH + kt * 32 + q * 8);
    bt = btag[c];
  }

  // ---- zero both h buffers (garbage rows must stay zero) ----
  {
    int4 z = {0, 0, 0, 0};
    reinterpret_cast<int4*>(hfrag)[tid] = z;
  }
  // ---- transitions (transposed, padded) ----
  if (tid < KK * KK) {
    int i = tid / KK, jj = tid - i * KK;
    trl[jj * 16 + i] = trans[tid];
  }
  __syncthreads();   // zero-pass complete before h0 fill

  // ---- h0 -> hfrag[0] valid rows (row = lb*4) ----
  if (tid < NB * HH) {
    int lb = tid >> 7, k = tid & 127;
    hfrag[0][frag_idx(lb * 4, k)] = f2bf(h0[(size_t)(bg * NB + lb) * HH + k]);
  }

  // ---- P stream: lane row -> batch q ----
  const unsigned short* pb0 =
      P16 + (size_t)(bg * NB + q) * (TT * 512) + ew * 4;
  ushort4 pA = *reinterpret_cast<const ushort4*>(pb0);
  ushort4 pB = *reinterpret_cast<const ushort4*>(pb0 + 512);

  const int hw_off = frag_idx(q * 4, ew);
  int nib = 0;
  __syncthreads();

  auto step = [&](int s, ushort4& pcur) {
    const int rb = s & 1;

    // h(s-1) A-fragments
    bf16x8 ha[4];
    if (s <= TT) {
      const bf16x8* hr = reinterpret_cast<const bf16x8*>(&hfrag[rb][0]) + l;
      #pragma unroll
      for (int kt = 0; kt < 4; ++kt) ha[kt] = hr[kt * 64];
    }

    if (s < TT) {
      // acc init from pregate quad (x@Wih^T + bias, offline)
      f32x4 acc[4];
      #pragma unroll
      for (int tt = 0; tt < 4; ++tt) {
        f32x4 z = {0.f, 0.f, 0.f, 0.f};
        acc[tt] = z;
      }
      acc[0][0] = bf2f(pcur.x); acc[1][0] = bf2f(pcur.y);
      acc[2][0] = bf2f(pcur.z); acc[3][0] = bf2f(pcur.w);

      // prefetch P(s+2) into the now-dead buffer
      if (s + 2 < TT)
        pcur = *reinterpret_cast<const ushort4*>(pb0 + (size_t)(s + 2) * 512);

      // h-side GEMM (critical path)
      #pragma unroll
      for (int kt = 0; kt < 4; ++kt) {
        #pragma unroll
        for (int tt = 0; tt < 4; ++tt)
          acc[tt] = __builtin_amdgcn_mfma_f32_16x16x32_bf16(ha[kt], wh[tt][kt], acc[tt], 0, 0, 0);
      }

      // cell update (1 row), merged-rcp activations:
      // sig(i)*tanh(g) = (1-b)*rcp((1+a)(1+b)); h = (1-ec)*rcp((1+ao)(1+ec))
      float ai = __builtin_amdgcn_exp2f(acc[0][0] * -1.44269504f);
      float bg_ = __builtin_amdgcn_exp2f(acc[2][0] * -2.88539008f);
      float af = __builtin_amdgcn_exp2f(acc[1][0] * -1.44269504f);
      float ao = __builtin_amdgcn_exp2f(acc[3][0] * -1.44269504f);
      float sitg = (1.0f - bg_) * __builtin_amdgcn_rcpf((1.0f + ai) * (1.0f + bg_));
      float sf = __builtin_amdgcn_rcpf(1.0f + af);
      cst = __fmaf_rn(sf, cst, sitg);
      float cc = fminf(fmaxf(cst, -30.0f), 30.0f);       // keep exp2 finite
      float ec = __builtin_amdgcn_exp2f(cc * -2.88539008f);
      float hv = (1.0f - ec) * __builtin_amdgcn_rcpf((1.0f + ao) * (1.0f + ec));
      hfrag[rb ^ 1][hw_off] = f2bf(hv);
    }

    // wave 0: emissions E(t=s-1) -> ering (batch q at D row q*4 -> accE[0])
    if (w == 0 && s >= 1 && s <= TT) {
      f32x4 accE = {0.f, 0.f, 0.f, 0.f};
      #pragma unroll
      for (int kt = 0; kt < 4; ++kt)
        accE = __builtin_amdgcn_mfma_f32_16x16x32_bf16(ha[kt], we[kt], accE, 0, 0, 0);
      ering[(s - 1) & 1][q * 16 + c] = accE[0] + bt;
    }

    // Viterbi DP (waves 4-7, lag 2): t = s-2, batch = w-4
    if (w >= 4 && s >= 2 && q == 0 && c < KK) {
      const int t_ = s - 2;
      const int b = w - 4;
      float Ev = ering[t_ & 1][b * 16 + c];
      float nv;
      if (t_ == 0) {
        nv = Ev;
      } else {
        float4 v0 = *reinterpret_cast<const float4*>(&vit[b * 16]);
        float4 v1 = *reinterpret_cast<const float4*>(&vit[b * 16 + 4]);
        float4 v2 = *reinterpret_cast<const float4*>(&vit[b * 16 + 8]);
        float4 t0 = *reinterpret_cast<const float4*>(&trl[c * 16]);
        float4 t1 = *reinterpret_cast<const float4*>(&trl[c * 16 + 4]);
        float4 t2 = *reinterpret_cast<const float4*>(&trl[c * 16 + 8]);
        float cand[KK] = {v0.x + t0.x, v0.y + t0.y, v0.z + t0.z, v0.w + t0.w,
                          v1.x + t1.x, v1.y + t1.y, v1.z + t1.z, v1.w + t1.w,
                          v2.x + t2.x, v2.y + t2.y, v2.z + t2.z, v2.w + t2.w};
        float g0 = fmaxf(fmaxf(cand[0], cand[1]), cand[2]);
        float g1 = fmaxf(fmaxf(cand[3], cand[4]), cand[5]);
        float g2 = fmaxf(fmaxf(cand[6], cand[7]), cand[8]);
        float g3 = fmaxf(fmaxf(cand[9], cand[10]), cand[11]);
        float best = fmaxf(fmaxf(g0, g1), fmaxf(g2, g3));
        int bi = 11;
        #pragma unroll
        for (int i = 10; i >= 0; --i) bi = (cand[i] == best) ? i : bi;   // first-max
        nv = Ev + best;
        if (t_ & 1) bp[(t_ >> 1) * (NB * 12) + b * 12 + c] =
                        (unsigned char)(nib | (bi << 4));
        else        nib = bi;
      }
      vit[b * 16 + c] = nv;
    }

    __syncthreads();
  };

  for (int s = 0; s < TT + 2; s += 2) {
    step(s, pA);
    step(s + 1, pB);
  }

  // ---- scores + backtrace (NB parallel chains) ----
  unsigned char* pb = reinterpret_cast<unsigned char*>(hfrag);  // reuse 8 KB
  if (tid < NB) {
    int b = tid;
    float best = vit[b * 16];
    int tag = 0;
    for (int jj = 1; jj < KK; ++jj) {
      float v = vit[b * 16 + jj];
      if (v > best) { best = v; tag = jj; }
    }
    out[bg * NB + b] = best;                    // scores
    pb[b * 512 + 511] = (unsigned char)tag;
    for (int t_ = TT - 1; t_ >= 1; --t_) {
      unsigned char byte = bp[(t_ >> 1) * (NB * 12) + b * 12 + tag];
      tag = (t_ & 1) ? (byte >> 4) & 15 : (byte & 15);
      pb[b * 512 + t_ - 1] = (unsigned char)tag;
    }
  }
  __syncthreads();

  #pragma unroll
  for (int i = 0; i < NB; ++i) {
    int idx = tid + i * 512;
    out[BB + (size_t)(bg * NB + (idx >> 9)) * TT + (idx & 511)] = (float)pb[idx];
  }
}

// ---------------------------------------------------------------------------
extern "C" void kernel_launch(void* const* d_in, const int* in_sizes, int n_in,
                              void* d_out, int out_size, void* d_ws, size_t ws_size,
                              hipStream_t stream) {
  const int*   sent  = (const int*)d_in[0];
  const float* h0    = (const float*)d_in[1];
  const float* c0    = (const float*)d_in[2];
  const float* embed = (const float*)d_in[3];
  const float* Wih   = (const float*)d_in[4];
  const float* Whh   = (const float*)d_in[5];
  const float* bih   = (const float*)d_in[6];
  const float* bhh   = (const float*)d_in[7];
  const float* Wtag  = (const float*)d_in[8];
  const float* btag  = (const float*)d_in[9];
  const float* trans = (const float*)d_in[10];
  float* out = (float*)d_out;

  // workspace layout: ebf [V*128 bf16] | wbf [128KB] | P16 [64MB]
  unsigned short* ebf = (unsigned short*)d_ws;
  unsigned short* wbf = ebf + (size_t)VV * 128;
  unsigned short* P16 = wbf + 8192 * 8;

  precast_kernel<<<(VV * 16 + 255) / 256, 256, 0, stream>>>(embed, ebf);
  wprep_kernel<<<32, 256, 0, stream>>>(Wih, bih, bhh, wbf);
  pregates_kernel<<<(BB * TT / 16) / 4, 256, 0, stream>>>(sent, ebf, wbf, P16);
  lstm_crf_fused<<<NBLK, 512, 60 * 1024, stream>>>(
      P16, Whh, h0, c0, Wtag, btag, trans, out);
}

// Round 14
// 533.884 us; speedup vs baseline: 1.2907x; 1.2907x over previous
//
#include <hip/hip_runtime.h>
#include <hip/hip_bf16.h>

#define BB 128   // batch
#define TT 512   // time
#define EE 100   // embed dim
#define HH 128   // hidden
#define KK 12    // tags
#define VV 50257 // vocab
#define NB 8     // batches per block (recurrent)
#define NBLK 16  // recurrent blocks

typedef short bf16x8 __attribute__((ext_vector_type(8)));
typedef float f32x4  __attribute__((ext_vector_type(4)));

__device__ __forceinline__ unsigned short f2bf(float x) {
  __hip_bfloat16 h = __float2bfloat16(x);
  return *reinterpret_cast<unsigned short*>(&h);
}
__device__ __forceinline__ float bf2f(unsigned short u) {
  return __uint_as_float(((unsigned)u) << 16);
}

__device__ __forceinline__ bf16x8 load8_bf(const float* p) {
  float4 a = *reinterpret_cast<const float4*>(p);
  float4 b = *reinterpret_cast<const float4*>(p + 4);
  bf16x8 r;
  r[0] = (short)f2bf(a.x); r[1] = (short)f2bf(a.y);
  r[2] = (short)f2bf(a.z); r[3] = (short)f2bf(a.w);
  r[4] = (short)f2bf(b.x); r[5] = (short)f2bf(b.y);
  r[6] = (short)f2bf(b.z); r[7] = (short)f2bf(b.w);
  return r;
}

// Wih fragment chunk with bias folded at k==EE, zeros past
__device__ __forceinline__ bf16x8 load8_bf_pad_bias(const float* row, int k0,
                                                    float bias) {
  bf16x8 r;
  #pragma unroll
  for (int i = 0; i < 8; ++i) {
    int k = k0 + i;
    unsigned short v = 0;
    if (k < EE) v = f2bf(row[k]);
    else if (k == EE) v = f2bf(bias);
    r[i] = (short)v;
  }
  return r;
}

// ushort index of (row b, col k) in A-frag-ordered tile (lane-linear)
__device__ __forceinline__ int frag_idx(int b, int k) {
  return ((k >> 5) << 9) + ((b + (((k >> 3) & 3) << 4)) << 3) + (k & 7);
}

// ---------------------------------------------------------------------------
// Kernel 0: precast embed -> bf16 [V][128]; col 100 = 1.0 (bias slot), rest 0.
// ---------------------------------------------------------------------------
__global__ __launch_bounds__(256) void precast_kernel(
    const float* __restrict__ embed, unsigned short* __restrict__ ebf)
{
  int id = blockIdx.x * 256 + threadIdx.x;
  if (id >= VV * 16) return;
  int v = id >> 4, g = id & 15;
  const float* row = embed + (size_t)v * EE;
  bf16x8 o;
  #pragma unroll
  for (int i = 0; i < 8; ++i) {
    int k = g * 8 + i;
    unsigned short u = 0;
    if (k < EE) u = f2bf(row[k]);
    else if (k == EE) u = 0x3F80;   // 1.0 bf16
    o[i] = (short)u;
  }
  *reinterpret_cast<bf16x8*>(ebf + (size_t)id * 8) = o;
}

// ---------------------------------------------------------------------------
// Kernel 1: Wih -> B-fragment table wbf[s8][tt][kt][lane] (bf16x8 each).
// ---------------------------------------------------------------------------
__global__ __launch_bounds__(256) void wprep_kernel(
    const float* __restrict__ Wih, const float* __restrict__ bih,
    const float* __restrict__ bhh, unsigned short* __restrict__ wbf)
{
  int id = blockIdx.x * 256 + threadIdx.x;   // 8192 frags
  if (id >= 8 * 4 * 4 * 64) return;
  int l = id & 63, kt = (id >> 6) & 3, tt = (id >> 8) & 3, s8 = id >> 10;
  int gcol = tt * HH + 16 * s8 + (l & 15);
  int k0 = kt * 32 + (l >> 4) * 8;
  float bias = bih[gcol] + bhh[gcol];
  bf16x8 r = load8_bf_pad_bias(Wih + (size_t)gcol * EE, k0, bias);
  *reinterpret_cast<bf16x8*>(wbf + (size_t)id * 8) = r;
}

// ---------------------------------------------------------------------------
// Kernel 2: pregates GEMM. P16[flat(b,t)][e][tt] bf16 quad-interleaved.
// ---------------------------------------------------------------------------
__global__ __launch_bounds__(256, 2) void pregates_kernel(
    const int* __restrict__ sent, const unsigned short* __restrict__ ebf,
    const unsigned short* __restrict__ wbf, unsigned short* __restrict__ P16)
{
  const int w = threadIdx.x >> 6, l = threadIdx.x & 63;
  const int c = l & 15, q = l >> 4;
  const int rt = blockIdx.x * 4 + w;
  const int flat = rt * 16 + c;               // this lane's A row
  const int b = flat >> 9, t = flat & 511;
  const int id = sent[b * TT + t];

  bf16x8 xa[4];
  #pragma unroll
  for (int kt = 0; kt < 4; ++kt)
    xa[kt] = *reinterpret_cast<const bf16x8*>(
        ebf + (size_t)id * 128 + kt * 32 + q * 8);

  const bf16x8* wb = reinterpret_cast<const bf16x8*>(wbf);
  #pragma unroll
  for (int s8 = 0; s8 < 8; ++s8) {
    f32x4 acc[4];
    #pragma unroll
    for (int tt = 0; tt < 4; ++tt) {
      f32x4 z = {0.f, 0.f, 0.f, 0.f};
      acc[tt] = z;
    }
    #pragma unroll
    for (int kt = 0; kt < 4; ++kt) {
      #pragma unroll
      for (int tt = 0; tt < 4; ++tt)
        acc[tt] = __builtin_amdgcn_mfma_f32_16x16x32_bf16(
            xa[kt], wb[((s8 * 4 + tt) * 4 + kt) * 64 + l], acc[tt], 0, 0, 0);
    }
    const int e = s8 * 16 + c;
    #pragma unroll
    for (int r4 = 0; r4 < 4; ++r4) {
      int fr = rt * 16 + q * 4 + r4;          // D row = (l>>4)*4 + reg
      ushort4 o = make_ushort4(f2bf(acc[0][r4]), f2bf(acc[1][r4]),
                               f2bf(acc[2][r4]), f2bf(acc[3][r4]));
      *reinterpret_cast<ushort4*>(P16 + ((size_t)fr * 128 + e) * 4) = o;
    }
  }
}

// ---------------------------------------------------------------------------
// Kernel 3: PURE recurrent LSTM. grid = 16 blocks (8 batches) x 512 threads.
// Batch lb at frag row ((lb>>1)*4 + (lb&1)); wave w owns e-strip [16w,16w+16)
// with gate-tiles {i,f,g,o}. Per step: ds_read(ha) -> P-quad acc init ->
// 16 MFMA -> merged-rcp activations -> ds_write(h). h(s-1) is stored to
// global hst from REGISTERS at the top of step s (full step of slack before
// the barrier's vmcnt drain). No emission/Viterbi in-loop (offline kernels).
// ---------------------------------------------------------------------------
__global__ __launch_bounds__(512, 2) void lstm_kernel(
    const unsigned short* __restrict__ P16, const float* __restrict__ Whh,
    const float* __restrict__ h0, const float* __restrict__ c0,
    unsigned short* __restrict__ hst)
{
  __shared__ __align__(16) unsigned short hfrag[2][2048];  // 8 KB h, frag order
  __shared__ __align__(16) unsigned int lpad[7168];        // 28 KB placement pad

  const int bg  = blockIdx.x;
  const int tid = threadIdx.x;
  const int w   = tid >> 6;         // wave 0..7
  const int l   = tid & 63;
  const int c   = l & 15;           // MFMA col within tile
  const int q   = l >> 4;           // row group; batches q*2+{0,1} at rows q*4+{0,1}
  const int ew  = 16 * w + c;       // this lane's gate column (e)

  // ---- weights: 4 gate-tiles {i,f,g,o} of e-strip (h-side only) ----
  bf16x8 wh[4][4];
  #pragma unroll
  for (int tt = 0; tt < 4; ++tt) {
    const int gcol = tt * HH + ew;
    #pragma unroll
    for (int kt = 0; kt < 4; ++kt)
      wh[tt][kt] = load8_bf(Whh + (size_t)gcol * HH + kt * 32 + q * 8);
  }

  // ---- cell state: lane (q,c) holds c for batches q*2+r, e=ew ----
  float cst[2];
  #pragma unroll
  for (int r = 0; r < 2; ++r)
    cst[r] = c0[(size_t)(bg * NB + q * 2 + r) * HH + ew];

  // ---- zero both h buffers + keep the placement pad alive (rule #17) ----
  {
    int4 z = {0, 0, 0, 0};
    reinterpret_cast<int4*>(hfrag)[tid] = z;
  }
  for (int i = tid; i < 7168; i += 512) lpad[i] = 0u;
  unsigned int keep = lpad[tid];
  asm volatile("" :: "v"(keep));
  __syncthreads();   // zero-pass complete before h0 fill

  // ---- h0 -> hfrag[0] valid rows ----
  for (int idx = tid; idx < NB * HH; idx += 512) {
    int lb = idx >> 7, k = idx & 127;
    int row = ((lb >> 1) << 2) + (lb & 1);
    hfrag[0][frag_idx(row, k)] = f2bf(h0[(size_t)(bg * NB + lb) * HH + k]);
  }

  // ---- P stream: per lane, rows r=0,1 -> batches bg*8+q*2+r ----
  const unsigned short* pb0 =
      P16 + (size_t)(bg * NB + q * 2 + 0) * (TT * 512) + ew * 4;
  const unsigned short* pb1 =
      P16 + (size_t)(bg * NB + q * 2 + 1) * (TT * 512) + ew * 4;
  ushort4 pA[2], pB[2];
  pA[0] = *reinterpret_cast<const ushort4*>(pb0);
  pA[1] = *reinterpret_cast<const ushort4*>(pb1);
  pB[0] = *reinterpret_cast<const ushort4*>(pb0 + 512);
  pB[1] = *reinterpret_cast<const ushort4*>(pb1 + 512);

  // ---- h history stream (per-lane register-delayed stores) ----
  unsigned short hp[2] = {0, 0};
  unsigned short* hb0 = hst + (size_t)(bg * NB + q * 2 + 0) * TT * HH + ew;
  unsigned short* hb1 = hst + (size_t)(bg * NB + q * 2 + 1) * TT * HH + ew;

  const int hw_off = frag_idx(q * 4, ew);
  __syncthreads();

  auto step = [&](int s, ushort4 (&pcur)[2]) {
    const int rb = s & 1;

    // store h(s-1) from registers: a full step before this step's drain
    if (s >= 1 && s <= TT) {
      hb0[(size_t)(s - 1) * HH] = hp[0];
      hb1[(size_t)(s - 1) * HH] = hp[1];
    }

    if (s < TT) {
      // h(s-1) A-fragments
      bf16x8 ha[4];
      const bf16x8* hr = reinterpret_cast<const bf16x8*>(&hfrag[rb][0]) + l;
      #pragma unroll
      for (int kt = 0; kt < 4; ++kt) ha[kt] = hr[kt * 64];

      // acc init from pregate quads (x@Wih^T + bias, offline)
      f32x4 acc[4];
      #pragma unroll
      for (int tt = 0; tt < 4; ++tt) {
        f32x4 z = {0.f, 0.f, 0.f, 0.f};
        acc[tt] = z;
      }
      acc[0][0] = bf2f(pcur[0].x); acc[1][0] = bf2f(pcur[0].y);
      acc[2][0] = bf2f(pcur[0].z); acc[3][0] = bf2f(pcur[0].w);
      acc[0][1] = bf2f(pcur[1].x); acc[1][1] = bf2f(pcur[1].y);
      acc[2][1] = bf2f(pcur[1].z); acc[3][1] = bf2f(pcur[1].w);

      // prefetch P(s+2) into the now-dead buffer
      if (s + 2 < TT) {
        pcur[0] = *reinterpret_cast<const ushort4*>(pb0 + (size_t)(s + 2) * 512);
        pcur[1] = *reinterpret_cast<const ushort4*>(pb1 + (size_t)(s + 2) * 512);
      }

      // h-side GEMM (critical path)
      #pragma unroll
      for (int kt = 0; kt < 4; ++kt) {
        #pragma unroll
        for (int tt = 0; tt < 4; ++tt)
          acc[tt] = __builtin_amdgcn_mfma_f32_16x16x32_bf16(ha[kt], wh[tt][kt], acc[tt], 0, 0, 0);
      }

      // cell update (2 rows), merged-rcp activations
      unsigned short* hwp = &hfrag[rb ^ 1][hw_off];
      #pragma unroll
      for (int r = 0; r < 2; ++r) {
        float ai  = __builtin_amdgcn_exp2f(acc[0][r] * -1.44269504f);
        float bgg = __builtin_amdgcn_exp2f(acc[2][r] * -2.88539008f);
        float af  = __builtin_amdgcn_exp2f(acc[1][r] * -1.44269504f);
        float ao  = __builtin_amdgcn_exp2f(acc[3][r] * -1.44269504f);
        float sitg = (1.0f - bgg) *
                     __builtin_amdgcn_rcpf((1.0f + ai) * (1.0f + bgg));
        float sf = __builtin_amdgcn_rcpf(1.0f + af);
        cst[r] = __fmaf_rn(sf, cst[r], sitg);
        float cc = fminf(fmaxf(cst[r], -30.0f), 30.0f);   // keep exp2 finite
        float ec = __builtin_amdgcn_exp2f(cc * -2.88539008f);
        float hv = (1.0f - ec) *
                   __builtin_amdgcn_rcpf((1.0f + ao) * (1.0f + ec));
        unsigned short hu = f2bf(hv);
        hwp[r * 8] = hu;
        hp[r] = hu;
      }
    }
    __syncthreads();
  };

  for (int s = 0; s < TT + 2; s += 2) {
    step(s, pA);
    step(s + 1, pB);
  }
}

// ---------------------------------------------------------------------------
// Kernel 4: emissions GEMM. E[flat(b,t)][16] f32 (cols 12..15 zero).
// grid = 1024 blocks x 256 threads (4 waves); wave -> 16-row tile of hst.
// ---------------------------------------------------------------------------
__global__ __launch_bounds__(256, 2) void emis_kernel(
    const unsigned short* __restrict__ hst, const float* __restrict__ Wtag,
    const float* __restrict__ btag, float* __restrict__ E)
{
  const int w = threadIdx.x >> 6, l = threadIdx.x & 63;
  const int c = l & 15, q = l >> 4;
  const int rt = blockIdx.x * 4 + w;

  bf16x8 we[4];
  #pragma unroll
  for (int kt = 0; kt < 4; ++kt) {
    #pragma unroll
    for (int i = 0; i < 8; ++i) we[kt][i] = 0;
  }
  float bt = 0.f;
  if (c < KK) {
    #pragma unroll
    for (int kt = 0; kt < 4; ++kt)
      we[kt] = load8_bf(Wtag + (size_t)c * HH + kt * 32 + q * 8);
    bt = btag[c];
  }

  bf16x8 ha[4];
  #pragma unroll
  for (int kt = 0; kt < 4; ++kt)
    ha[kt] = *reinterpret_cast<const bf16x8*>(
        hst + (size_t)(rt * 16 + c) * HH + kt * 32 + q * 8);

  f32x4 acc = {0.f, 0.f, 0.f, 0.f};
  #pragma unroll
  for (int kt = 0; kt < 4; ++kt)
    acc = __builtin_amdgcn_mfma_f32_16x16x32_bf16(ha[kt], we[kt], acc, 0, 0, 0);

  #pragma unroll
  for (int r = 0; r < 4; ++r)
    E[(size_t)(rt * 16 + q * 4 + r) * 16 + c] = acc[r] + bt;
}

// ---------------------------------------------------------------------------
// Kernel 5: Viterbi DP + backtrace. grid = 128 blocks x 64 threads (1 wave,
// one batch per block). Lane j<12 owns tag j; E prefetched 8 steps ahead.
// ---------------------------------------------------------------------------
__global__ __launch_bounds__(64) void vit_kernel(
    const float* __restrict__ E, const float* __restrict__ trans,
    float* __restrict__ out)
{
  __shared__ __align__(16) float trl[KK * 16];   // trl[j*16+i] = trans[i][j]
  __shared__ __align__(16) float vit[16];
  __shared__ unsigned char bp[TT * KK];          // 6 KB backpointers
  __shared__ unsigned char path[TT];

  const int b = blockIdx.x, tid = threadIdx.x;
  if (tid < KK * KK) {
    int i = tid / KK, jj = tid - i * KK;
    trl[jj * 16 + i] = trans[tid];
  }
  __syncthreads();

  const int j = tid;
  const float* Eb = E + (size_t)b * TT * 16 + j;

  float cur[8], nxt[8];
  if (j < 16) {
    #pragma unroll
    for (int i = 0; i < 8; ++i) cur[i] = Eb[i * 16];
  }

  for (int tb = 0; tb < TT; tb += 8) {
    if (j < 16 && tb + 8 < TT) {
      #pragma unroll
      for (int i = 0; i < 8; ++i) nxt[i] = Eb[(size_t)(tb + 8 + i) * 16];
    }
    #pragma unroll
    for (int i = 0; i < 8; ++i) {
      const int t = tb + i;
      if (j < KK) {
        float Ev = cur[i];
        float nv;
        if (t == 0) {
          nv = Ev;
        } else {
          float4 v0 = *reinterpret_cast<const float4*>(&vit[0]);
          float4 v1 = *reinterpret_cast<const float4*>(&vit[4]);
          float4 v2 = *reinterpret_cast<const float4*>(&vit[8]);
          float4 t0 = *reinterpret_cast<const float4*>(&trl[j * 16]);
          float4 t1 = *reinterpret_cast<const float4*>(&trl[j * 16 + 4]);
          float4 t2 = *reinterpret_cast<const float4*>(&trl[j * 16 + 8]);
          float cand[KK] = {v0.x + t0.x, v0.y + t0.y, v0.z + t0.z, v0.w + t0.w,
                            v1.x + t1.x, v1.y + t1.y, v1.z + t1.z, v1.w + t1.w,
                            v2.x + t2.x, v2.y + t2.y, v2.z + t2.z, v2.w + t2.w};
          float g0 = fmaxf(fmaxf(cand[0], cand[1]), cand[2]);
          float g1 = fmaxf(fmaxf(cand[3], cand[4]), cand[5]);
          float g2 = fmaxf(fmaxf(cand[6], cand[7]), cand[8]);
          float g3 = fmaxf(fmaxf(cand[9], cand[10]), cand[11]);
          float best = fmaxf(fmaxf(g0, g1), fmaxf(g2, g3));
          int bi = 11;
          #pragma unroll
          for (int k = 10; k >= 0; --k) bi = (cand[k] == best) ? k : bi;  // first-max
          nv = Ev + best;
          bp[t * KK + j] = (unsigned char)bi;
        }
        vit[j] = nv;
      }
      __syncthreads();
    }
    #pragma unroll
    for (int i = 0; i < 8; ++i) cur[i] = nxt[i];
  }

  // ---- score + backtrace ----
  if (tid == 0) {
    float best = vit[0];
    int tag = 0;
    for (int jj = 1; jj < KK; ++jj)
      if (vit[jj] > best) { best = vit[jj]; tag = jj; }
    out[b] = best;
    path[TT - 1] = (unsigned char)tag;
    for (int t = TT - 1; t >= 1; --t) {
      tag = bp[t * KK + tag];
      path[t - 1] = (unsigned char)tag;
    }
  }
  __syncthreads();

  #pragma unroll
  for (int i = 0; i < 8; ++i)
    out[BB + (size_t)b * TT + tid + i * 64] = (float)path[tid + i * 64];
}

// ---------------------------------------------------------------------------
extern "C" void kernel_launch(void* const* d_in, const int* in_sizes, int n_in,
                              void* d_out, int out_size, void* d_ws, size_t ws_size,
                              hipStream_t stream) {
  const int*   sent  = (const int*)d_in[0];
  const float* h0    = (const float*)d_in[1];
  const float* c0    = (const float*)d_in[2];
  const float* embed = (const float*)d_in[3];
  const float* Wih   = (const float*)d_in[4];
  const float* Whh   = (const float*)d_in[5];
  const float* bih   = (const float*)d_in[6];
  const float* bhh   = (const float*)d_in[7];
  const float* Wtag  = (const float*)d_in[8];
  const float* btag  = (const float*)d_in[9];
  const float* trans = (const float*)d_in[10];
  float* out = (float*)d_out;

  // workspace: ebf 12.9MB | wbf 128KB | P16 64MB | hst 16MB | E 4MB  (~97MB)
  unsigned short* ebf = (unsigned short*)d_ws;
  unsigned short* wbf = ebf + (size_t)VV * 128;
  unsigned short* P16 = wbf + 8192 * 8;
  unsigned short* hst = P16 + (size_t)BB * TT * 512;
  float*          Ebf = (float*)(hst + (size_t)BB * TT * HH);

  precast_kernel<<<(VV * 16 + 255) / 256, 256, 0, stream>>>(embed, ebf);
  wprep_kernel<<<32, 256, 0, stream>>>(Wih, bih, bhh, wbf);
  pregates_kernel<<<(BB * TT / 16) / 4, 256, 0, stream>>>(sent, ebf, wbf, P16);
  lstm_kernel<<<NBLK, 512, 0, stream>>>(P16, Whh, h0, c0, hst);
  emis_kernel<<<(BB * TT / 16) / 4, 256, 0, stream>>>(hst, Wtag, btag, Ebf);
  vit_kernel<<<BB, 64, 0, stream>>>(Ebf, trans, out);
}

// Round 15
// 530.800 us; speedup vs baseline: 1.2982x; 1.0058x over previous
//
#include <hip/hip_runtime.h>
#include <hip/hip_bf16.h>

#define BB 128   // batch
#define TT 512   // time
#define EE 100   // embed dim
#define HH 128   // hidden
#define KK 12    // tags
#define VV 50257 // vocab
#define NB 8     // batches per block (recurrent)
#define NBLK 16  // recurrent blocks
#define NPRE ((VV * 16 + 255) / 256)

typedef short bf16x8 __attribute__((ext_vector_type(8)));
typedef float f32x4  __attribute__((ext_vector_type(4)));

__device__ __forceinline__ unsigned short f2bf(float x) {
  __hip_bfloat16 h = __float2bfloat16(x);
  return *reinterpret_cast<unsigned short*>(&h);
}
__device__ __forceinline__ float bf2f(unsigned short u) {
  return __uint_as_float(((unsigned)u) << 16);
}

__device__ __forceinline__ bf16x8 load8_bf(const float* p) {
  float4 a = *reinterpret_cast<const float4*>(p);
  float4 b = *reinterpret_cast<const float4*>(p + 4);
  bf16x8 r;
  r[0] = (short)f2bf(a.x); r[1] = (short)f2bf(a.y);
  r[2] = (short)f2bf(a.z); r[3] = (short)f2bf(a.w);
  r[4] = (short)f2bf(b.x); r[5] = (short)f2bf(b.y);
  r[6] = (short)f2bf(b.z); r[7] = (short)f2bf(b.w);
  return r;
}

// Wih fragment chunk with bias folded at k==EE, zeros past
__device__ __forceinline__ bf16x8 load8_bf_pad_bias(const float* row, int k0,
                                                    float bias) {
  bf16x8 r;
  #pragma unroll
  for (int i = 0; i < 8; ++i) {
    int k = k0 + i;
    unsigned short v = 0;
    if (k < EE) v = f2bf(row[k]);
    else if (k == EE) v = f2bf(bias);
    r[i] = (short)v;
  }
  return r;
}

// ushort index of (row b, col k) in A-frag-ordered tile (lane-linear)
__device__ __forceinline__ int frag_idx(int b, int k) {
  return ((k >> 5) << 9) + ((b + (((k >> 3) & 3) << 4)) << 3) + (k & 7);
}

// LDS-only barrier: waits DS ops, leaves global loads/stores in flight.
// T4 pattern: never drain vmcnt(0) inside the sequential loop.
__device__ __forceinline__ void lds_barrier() {
  asm volatile("s_waitcnt lgkmcnt(0)\n\ts_barrier" ::: "memory");
}

// ---------------------------------------------------------------------------
// Kernel 0: precast embed -> bf16 [V][128] (col 100 = 1.0 bias slot), PLUS
// (last 32 blocks) wprep: Wih -> B-fragment table wbf[s8][tt][kt][lane].
// ---------------------------------------------------------------------------
__global__ __launch_bounds__(256) void prep_kernel(
    const float* __restrict__ embed, const float* __restrict__ Wih,
    const float* __restrict__ bih, const float* __restrict__ bhh,
    unsigned short* __restrict__ ebf, unsigned short* __restrict__ wbf)
{
  if (blockIdx.x < NPRE) {
    int id = blockIdx.x * 256 + threadIdx.x;
    if (id >= VV * 16) return;
    int v = id >> 4, g = id & 15;
    const float* row = embed + (size_t)v * EE;
    bf16x8 o;
    #pragma unroll
    for (int i = 0; i < 8; ++i) {
      int k = g * 8 + i;
      unsigned short u = 0;
      if (k < EE) u = f2bf(row[k]);
      else if (k == EE) u = 0x3F80;   // 1.0 bf16
      o[i] = (short)u;
    }
    *reinterpret_cast<bf16x8*>(ebf + (size_t)id * 8) = o;
  } else {
    int id = (blockIdx.x - NPRE) * 256 + threadIdx.x;   // 8192 frags
    if (id >= 8 * 4 * 4 * 64) return;
    int l = id & 63, kt = (id >> 6) & 3, tt = (id >> 8) & 3, s8 = id >> 10;
    int gcol = tt * HH + 16 * s8 + (l & 15);
    int k0 = kt * 32 + (l >> 4) * 8;
    float bias = bih[gcol] + bhh[gcol];
    bf16x8 r = load8_bf_pad_bias(Wih + (size_t)gcol * EE, k0, bias);
    *reinterpret_cast<bf16x8*>(wbf + (size_t)id * 8) = r;
  }
}

// ---------------------------------------------------------------------------
// Kernel 1: pregates GEMM. P16[flat(b,t)][e][tt] bf16 quad-interleaved.
// ---------------------------------------------------------------------------
__global__ __launch_bounds__(256, 2) void pregates_kernel(
    const int* __restrict__ sent, const unsigned short* __restrict__ ebf,
    const unsigned short* __restrict__ wbf, unsigned short* __restrict__ P16)
{
  const int w = threadIdx.x >> 6, l = threadIdx.x & 63;
  const int c = l & 15, q = l >> 4;
  const int rt = blockIdx.x * 4 + w;
  const int flat = rt * 16 + c;               // this lane's A row
  const int b = flat >> 9, t = flat & 511;
  const int id = sent[b * TT + t];

  bf16x8 xa[4];
  #pragma unroll
  for (int kt = 0; kt < 4; ++kt)
    xa[kt] = *reinterpret_cast<const bf16x8*>(
        ebf + (size_t)id * 128 + kt * 32 + q * 8);

  const bf16x8* wb = reinterpret_cast<const bf16x8*>(wbf);
  #pragma unroll
  for (int s8 = 0; s8 < 8; ++s8) {
    f32x4 acc[4];
    #pragma unroll
    for (int tt = 0; tt < 4; ++tt) {
      f32x4 z = {0.f, 0.f, 0.f, 0.f};
      acc[tt] = z;
    }
    #pragma unroll
    for (int kt = 0; kt < 4; ++kt) {
      #pragma unroll
      for (int tt = 0; tt < 4; ++tt)
        acc[tt] = __builtin_amdgcn_mfma_f32_16x16x32_bf16(
            xa[kt], wb[((s8 * 4 + tt) * 4 + kt) * 64 + l], acc[tt], 0, 0, 0);
    }
    const int e = s8 * 16 + c;
    #pragma unroll
    for (int r4 = 0; r4 < 4; ++r4) {
      int fr = rt * 16 + q * 4 + r4;          // D row = (l>>4)*4 + reg
      ushort4 o = make_ushort4(f2bf(acc[0][r4]), f2bf(acc[1][r4]),
                               f2bf(acc[2][r4]), f2bf(acc[3][r4]));
      *reinterpret_cast<ushort4*>(P16 + ((size_t)fr * 128 + e) * 4) = o;
    }
  }
}

// ---------------------------------------------------------------------------
// Kernel 2: PURE recurrent LSTM. grid = 16 blocks (8 batches) x 512 threads.
// Per step: ds_read(ha) -> P-quad acc init -> 16 MFMA -> merged-rcp
// activations -> ds_write(h) -> LDS-ONLY barrier (P prefetch + hst stores
// stay in flight across it; compiler inserts counted vmcnt before use).
// 76 KB static pad -> 84 KB/block -> exactly 1 block/CU.
// ---------------------------------------------------------------------------
__global__ __launch_bounds__(512, 2) void lstm_kernel(
    const unsigned short* __restrict__ P16, const float* __restrict__ Whh,
    const float* __restrict__ h0, const float* __restrict__ c0,
    unsigned short* __restrict__ hst)
{
  __shared__ __align__(16) unsigned short hfrag[2][2048];  // 8 KB h, frag order
  __shared__ __align__(16) unsigned int lpad[19456];       // 76 KB placement pad

  const int bg  = blockIdx.x;
  const int tid = threadIdx.x;
  const int w   = tid >> 6;         // wave 0..7
  const int l   = tid & 63;
  const int c   = l & 15;           // MFMA col within tile
  const int q   = l >> 4;           // row group; batches q*2+{0,1} at rows q*4+{0,1}
  const int ew  = 16 * w + c;       // this lane's gate column (e)

  // ---- weights: 4 gate-tiles {i,f,g,o} of e-strip (h-side only) ----
  bf16x8 wh[4][4];
  #pragma unroll
  for (int tt = 0; tt < 4; ++tt) {
    const int gcol = tt * HH + ew;
    #pragma unroll
    for (int kt = 0; kt < 4; ++kt)
      wh[tt][kt] = load8_bf(Whh + (size_t)gcol * HH + kt * 32 + q * 8);
  }

  // ---- cell state: lane (q,c) holds c for batches q*2+r, e=ew ----
  float cst[2];
  #pragma unroll
  for (int r = 0; r < 2; ++r)
    cst[r] = c0[(size_t)(bg * NB + q * 2 + r) * HH + ew];

  // ---- zero both h buffers + keep the placement pad alive (rule #17) ----
  {
    int4 z = {0, 0, 0, 0};
    reinterpret_cast<int4*>(hfrag)[tid] = z;
  }
  for (int i = tid; i < 19456; i += 512) lpad[i] = 0u;
  unsigned int keep = lpad[tid];
  asm volatile("" :: "v"(keep));
  __syncthreads();   // zero-pass complete before h0 fill

  // ---- h0 -> hfrag[0] valid rows ----
  for (int idx = tid; idx < NB * HH; idx += 512) {
    int lb = idx >> 7, k = idx & 127;
    int row = ((lb >> 1) << 2) + (lb & 1);
    hfrag[0][frag_idx(row, k)] = f2bf(h0[(size_t)(bg * NB + lb) * HH + k]);
  }

  // ---- P stream: per lane, rows r=0,1 -> batches bg*8+q*2+r ----
  const unsigned short* pb0 =
      P16 + (size_t)(bg * NB + q * 2 + 0) * (TT * 512) + ew * 4;
  const unsigned short* pb1 =
      P16 + (size_t)(bg * NB + q * 2 + 1) * (TT * 512) + ew * 4;
  ushort4 pA[2], pB[2];
  pA[0] = *reinterpret_cast<const ushort4*>(pb0);
  pA[1] = *reinterpret_cast<const ushort4*>(pb1);
  pB[0] = *reinterpret_cast<const ushort4*>(pb0 + 512);
  pB[1] = *reinterpret_cast<const ushort4*>(pb1 + 512);

  // ---- h history stream (per-lane register-delayed stores) ----
  unsigned short hp[2] = {0, 0};
  unsigned short* hb0 = hst + (size_t)(bg * NB + q * 2 + 0) * TT * HH + ew;
  unsigned short* hb1 = hst + (size_t)(bg * NB + q * 2 + 1) * TT * HH + ew;

  const int hw_off = frag_idx(q * 4, ew);
  __syncthreads();

  auto step = [&](int s, ushort4 (&pcur)[2]) {
    const int rb = s & 1;

    // store h(s-1) from registers: a full step of slack, never drained in-loop
    if (s >= 1 && s <= TT) {
      hb0[(size_t)(s - 1) * HH] = hp[0];
      hb1[(size_t)(s - 1) * HH] = hp[1];
    }

    if (s < TT) {
      // h(s-1) A-fragments
      bf16x8 ha[4];
      const bf16x8* hr = reinterpret_cast<const bf16x8*>(&hfrag[rb][0]) + l;
      #pragma unroll
      for (int kt = 0; kt < 4; ++kt) ha[kt] = hr[kt * 64];

      // acc init from pregate quads (x@Wih^T + bias, offline)
      f32x4 acc[4];
      #pragma unroll
      for (int tt = 0; tt < 4; ++tt) {
        f32x4 z = {0.f, 0.f, 0.f, 0.f};
        acc[tt] = z;
      }
      acc[0][0] = bf2f(pcur[0].x); acc[1][0] = bf2f(pcur[0].y);
      acc[2][0] = bf2f(pcur[0].z); acc[3][0] = bf2f(pcur[0].w);
      acc[0][1] = bf2f(pcur[1].x); acc[1][1] = bf2f(pcur[1].y);
      acc[2][1] = bf2f(pcur[1].z); acc[3][1] = bf2f(pcur[1].w);

      // prefetch P(s+2) into the now-dead buffer (stays in flight)
      if (s + 2 < TT) {
        pcur[0] = *reinterpret_cast<const ushort4*>(pb0 + (size_t)(s + 2) * 512);
        pcur[1] = *reinterpret_cast<const ushort4*>(pb1 + (size_t)(s + 2) * 512);
      }

      // h-side GEMM (critical path)
      #pragma unroll
      for (int kt = 0; kt < 4; ++kt) {
        #pragma unroll
        for (int tt = 0; tt < 4; ++tt)
          acc[tt] = __builtin_amdgcn_mfma_f32_16x16x32_bf16(ha[kt], wh[tt][kt], acc[tt], 0, 0, 0);
      }

      // cell update (2 rows), merged-rcp activations
      unsigned short* hwp = &hfrag[rb ^ 1][hw_off];
      #pragma unroll
      for (int r = 0; r < 2; ++r) {
        float ai  = __builtin_amdgcn_exp2f(acc[0][r] * -1.44269504f);
        float bgg = __builtin_amdgcn_exp2f(acc[2][r] * -2.88539008f);
        float af  = __builtin_amdgcn_exp2f(acc[1][r] * -1.44269504f);
        float ao  = __builtin_amdgcn_exp2f(acc[3][r] * -1.44269504f);
        float sitg = (1.0f - bgg) *
                     __builtin_amdgcn_rcpf((1.0f + ai) * (1.0f + bgg));
        float sf = __builtin_amdgcn_rcpf(1.0f + af);
        cst[r] = __fmaf_rn(sf, cst[r], sitg);
        float cc = __builtin_amdgcn_fmed3f(cst[r], -30.0f, 30.0f);
        float ec = __builtin_amdgcn_exp2f(cc * -2.88539008f);
        float hv = (1.0f - ec) *
                   __builtin_amdgcn_rcpf((1.0f + ao) * (1.0f + ec));
        unsigned short hu = f2bf(hv);
        hwp[r * 8] = hu;
        hp[r] = hu;
      }
    }
    lds_barrier();   // LDS-visibility only; VMEM stays in flight
  };

  for (int s = 0; s < TT + 2; s += 2) {
    step(s, pA);
    step(s + 1, pB);
  }
}

// ---------------------------------------------------------------------------
// Kernel 3: fused emissions + Viterbi DP + backtrace. grid = 128 blocks x 64
// threads (1 wave, one batch). Per 16-t tile: A-frags from hst -> 4 MFMA ->
// ering -> 16 DP steps (lane j<12 owns tag j).
// ---------------------------------------------------------------------------
__global__ __launch_bounds__(64) void vit_kernel(
    const unsigned short* __restrict__ hst, const float* __restrict__ Wtag,
    const float* __restrict__ btag, const float* __restrict__ trans,
    float* __restrict__ out)
{
  __shared__ __align__(16) float trl[KK * 16];   // trl[j*16+i] = trans[i][j]
  __shared__ __align__(16) float vbuf[16];
  __shared__ __align__(16) float ering[16 * 16];
  __shared__ unsigned char bp[TT * KK];          // 6 KB backpointers
  __shared__ unsigned char path[TT];

  const int b = blockIdx.x, tid = threadIdx.x;
  const int c = tid & 15, q = tid >> 4;

  if (tid < KK * KK) {
    int i = tid / KK, jj = tid - i * KK;
    trl[jj * 16 + i] = trans[tid];
  }

  // emission weight fragments (col = c; zero for c >= 12)
  bf16x8 we[4];
  #pragma unroll
  for (int kt = 0; kt < 4; ++kt) {
    #pragma unroll
    for (int i = 0; i < 8; ++i) we[kt][i] = 0;
  }
  float bt = 0.f;
  if (c < KK) {
    #pragma unroll
    for (int kt = 0; kt < 4; ++kt)
      we[kt] = load8_bf(Wtag + (size_t)c * HH + kt * 32 + q * 8);
    bt = btag[c];
  }
  const unsigned short* hb = hst + (size_t)b * TT * HH;
  __syncthreads();

  for (int tb = 0; tb < TT; tb += 16) {
    // A-frags: rows t = tb + c
    bf16x8 ha[4];
    #pragma unroll
    for (int kt = 0; kt < 4; ++kt)
      ha[kt] = *reinterpret_cast<const bf16x8*>(
          hb + (size_t)(tb + c) * HH + kt * 32 + q * 8);
    f32x4 accE = {0.f, 0.f, 0.f, 0.f};
    #pragma unroll
    for (int kt = 0; kt < 4; ++kt)
      accE = __builtin_amdgcn_mfma_f32_16x16x32_bf16(ha[kt], we[kt], accE, 0, 0, 0);
    __syncthreads();   // previous tile's DP reads done
    #pragma unroll
    for (int r = 0; r < 4; ++r)
      ering[(q * 4 + r) * 16 + c] = accE[r] + bt;   // local t = q*4+r, tag = c
    __syncthreads();

    #pragma unroll
    for (int i = 0; i < 16; ++i) {
      const int t = tb + i;
      if (tid < KK) {
        const int j = tid;
        float Ev = ering[i * 16 + j];
        float nv;
        if (t == 0) {
          nv = Ev;
        } else {
          float4 v0 = *reinterpret_cast<const float4*>(&vbuf[0]);
          float4 v1 = *reinterpret_cast<const float4*>(&vbuf[4]);
          float4 v2 = *reinterpret_cast<const float4*>(&vbuf[8]);
          float4 t0 = *reinterpret_cast<const float4*>(&trl[j * 16]);
          float4 t1 = *reinterpret_cast<const float4*>(&trl[j * 16 + 4]);
          float4 t2 = *reinterpret_cast<const float4*>(&trl[j * 16 + 8]);
          float cand[KK] = {v0.x + t0.x, v0.y + t0.y, v0.z + t0.z, v0.w + t0.w,
                            v1.x + t1.x, v1.y + t1.y, v1.z + t1.z, v1.w + t1.w,
                            v2.x + t2.x, v2.y + t2.y, v2.z + t2.z, v2.w + t2.w};
          float g0 = fmaxf(fmaxf(cand[0], cand[1]), cand[2]);
          float g1 = fmaxf(fmaxf(cand[3], cand[4]), cand[5]);
          float g2 = fmaxf(fmaxf(cand[6], cand[7]), cand[8]);
          float g3 = fmaxf(fmaxf(cand[9], cand[10]), cand[11]);
          float best = fmaxf(fmaxf(g0, g1), fmaxf(g2, g3));
          int bi = 11;
          #pragma unroll
          for (int k = 10; k >= 0; --k) bi = (cand[k] == best) ? k : bi;  // first-max
          nv = Ev + best;
          bp[t * KK + j] = (unsigned char)bi;
        }
        vbuf[j] = nv;
      }
      __syncthreads();
    }
  }

  // ---- score + backtrace ----
  if (tid == 0) {
    float best = vbuf[0];
    int tag = 0;
    for (int jj = 1; jj < KK; ++jj)
      if (vbuf[jj] > best) { best = vbuf[jj]; tag = jj; }
    out[b] = best;
    path[TT - 1] = (unsigned char)tag;
    for (int t = TT - 1; t >= 1; --t) {
      tag = bp[t * KK + tag];
      path[t - 1] = (unsigned char)tag;
    }
  }
  __syncthreads();

  #pragma unroll
  for (int i = 0; i < 8; ++i)
    out[BB + (size_t)b * TT + tid + i * 64] = (float)path[tid + i * 64];
}

// ---------------------------------------------------------------------------
extern "C" void kernel_launch(void* const* d_in, const int* in_sizes, int n_in,
                              void* d_out, int out_size, void* d_ws, size_t ws_size,
                              hipStream_t stream) {
  const int*   sent  = (const int*)d_in[0];
  const float* h0    = (const float*)d_in[1];
  const float* c0    = (const float*)d_in[2];
  const float* embed = (const float*)d_in[3];
  const float* Wih   = (const float*)d_in[4];
  const float* Whh   = (const float*)d_in[5];
  const float* bih   = (const float*)d_in[6];
  const float* bhh   = (const float*)d_in[7];
  const float* Wtag  = (const float*)d_in[8];
  const float* btag  = (const float*)d_in[9];
  const float* trans = (const float*)d_in[10];
  float* out = (float*)d_out;

  // workspace: ebf 12.9MB | wbf 128KB | P16 64MB | hst 16MB   (~93MB)
  unsigned short* ebf = (unsigned short*)d_ws;
  unsigned short* wbf = ebf + (size_t)VV * 128;
  unsigned short* P16 = wbf + 8192 * 8;
  unsigned short* hst = P16 + (size_t)BB * TT * 512;

  prep_kernel<<<NPRE + 32, 256, 0, stream>>>(embed, Wih, bih, bhh, ebf, wbf);
  pregates_kernel<<<(BB * TT / 16) / 4, 256, 0, stream>>>(sent, ebf, wbf, P16);
  lstm_kernel<<<NBLK, 512, 0, stream>>>(P16, Whh, h0, c0, hst);
  vit_kernel<<<BB, 64, 0, stream>>>(hst, Wtag, btag, trans, out);
}

// Round 16
// 515.842 us; speedup vs baseline: 1.3358x; 1.0290x over previous
//
#include <hip/hip_runtime.h>
#include <hip/hip_bf16.h>

#define BB 128   // batch
#define TT 512   // time
#define EE 100   // embed dim
#define HH 128   // hidden
#define KK 12    // tags
#define VV 50257 // vocab
#define NB 8     // batches per block (recurrent)
#define NBLK 16  // recurrent blocks
#define NPRE ((VV * 16 + 255) / 256)

typedef short bf16x8 __attribute__((ext_vector_type(8)));
typedef float f32x4  __attribute__((ext_vector_type(4)));

__device__ __forceinline__ unsigned short f2bf(float x) {
  __hip_bfloat16 h = __float2bfloat16(x);
  return *reinterpret_cast<unsigned short*>(&h);
}
__device__ __forceinline__ float bf2f(unsigned short u) {
  return __uint_as_float(((unsigned)u) << 16);
}

__device__ __forceinline__ bf16x8 load8_bf(const float* p) {
  float4 a = *reinterpret_cast<const float4*>(p);
  float4 b = *reinterpret_cast<const float4*>(p + 4);
  bf16x8 r;
  r[0] = (short)f2bf(a.x); r[1] = (short)f2bf(a.y);
  r[2] = (short)f2bf(a.z); r[3] = (short)f2bf(a.w);
  r[4] = (short)f2bf(b.x); r[5] = (short)f2bf(b.y);
  r[6] = (short)f2bf(b.z); r[7] = (short)f2bf(b.w);
  return r;
}

// Wih fragment chunk with bias folded at k==EE, zeros past
__device__ __forceinline__ bf16x8 load8_bf_pad_bias(const float* row, int k0,
                                                    float bias) {
  bf16x8 r;
  #pragma unroll
  for (int i = 0; i < 8; ++i) {
    int k = k0 + i;
    unsigned short v = 0;
    if (k < EE) v = f2bf(row[k]);
    else if (k == EE) v = f2bf(bias);
    r[i] = (short)v;
  }
  return r;
}

// ushort index of (row b, col k) in A-frag-ordered tile (lane-linear)
__device__ __forceinline__ int frag_idx(int b, int k) {
  return ((k >> 5) << 9) + ((b + (((k >> 3) & 3) << 4)) << 3) + (k & 7);
}

// LDS-only barrier: waits DS ops, leaves global loads/stores in flight.
__device__ __forceinline__ void lds_barrier() {
  asm volatile("s_waitcnt lgkmcnt(0)\n\ts_barrier" ::: "memory");
}

// ---------------------------------------------------------------------------
// Kernel 0: precast embed -> bf16 [V][128] (col 100 = 1.0 bias slot), PLUS
// (last 32 blocks) wprep: Wih -> B-fragment table wbf[s8][tt][kt][lane].
// ---------------------------------------------------------------------------
__global__ __launch_bounds__(256) void prep_kernel(
    const float* __restrict__ embed, const float* __restrict__ Wih,
    const float* __restrict__ bih, const float* __restrict__ bhh,
    unsigned short* __restrict__ ebf, unsigned short* __restrict__ wbf)
{
  if (blockIdx.x < NPRE) {
    int id = blockIdx.x * 256 + threadIdx.x;
    if (id >= VV * 16) return;
    int v = id >> 4, g = id & 15;
    const float* row = embed + (size_t)v * EE;
    bf16x8 o;
    #pragma unroll
    for (int i = 0; i < 8; ++i) {
      int k = g * 8 + i;
      unsigned short u = 0;
      if (k < EE) u = f2bf(row[k]);
      else if (k == EE) u = 0x3F80;   // 1.0 bf16
      o[i] = (short)u;
    }
    *reinterpret_cast<bf16x8*>(ebf + (size_t)id * 8) = o;
  } else {
    int id = (blockIdx.x - NPRE) * 256 + threadIdx.x;   // 8192 frags
    if (id >= 8 * 4 * 4 * 64) return;
    int l = id & 63, kt = (id >> 6) & 3, tt = (id >> 8) & 3, s8 = id >> 10;
    int gcol = tt * HH + 16 * s8 + (l & 15);
    int k0 = kt * 32 + (l >> 4) * 8;
    float bias = bih[gcol] + bhh[gcol];
    bf16x8 r = load8_bf_pad_bias(Wih + (size_t)gcol * EE, k0, bias);
    *reinterpret_cast<bf16x8*>(wbf + (size_t)id * 8) = r;
  }
}

// ---------------------------------------------------------------------------
// Kernel 1: pregates GEMM. P16[flat(b,t)][e][tt] bf16 quad-interleaved.
// ---------------------------------------------------------------------------
__global__ __launch_bounds__(256, 2) void pregates_kernel(
    const int* __restrict__ sent, const unsigned short* __restrict__ ebf,
    const unsigned short* __restrict__ wbf, unsigned short* __restrict__ P16)
{
  const int w = threadIdx.x >> 6, l = threadIdx.x & 63;
  const int c = l & 15, q = l >> 4;
  const int rt = blockIdx.x * 4 + w;
  const int flat = rt * 16 + c;               // this lane's A row
  const int b = flat >> 9, t = flat & 511;
  const int id = sent[b * TT + t];

  bf16x8 xa[4];
  #pragma unroll
  for (int kt = 0; kt < 4; ++kt)
    xa[kt] = *reinterpret_cast<const bf16x8*>(
        ebf + (size_t)id * 128 + kt * 32 + q * 8);

  const bf16x8* wb = reinterpret_cast<const bf16x8*>(wbf);
  #pragma unroll
  for (int s8 = 0; s8 < 8; ++s8) {
    f32x4 acc[4];
    #pragma unroll
    for (int tt = 0; tt < 4; ++tt) {
      f32x4 z = {0.f, 0.f, 0.f, 0.f};
      acc[tt] = z;
    }
    #pragma unroll
    for (int kt = 0; kt < 4; ++kt) {
      #pragma unroll
      for (int tt = 0; tt < 4; ++tt)
        acc[tt] = __builtin_amdgcn_mfma_f32_16x16x32_bf16(
            xa[kt], wb[((s8 * 4 + tt) * 4 + kt) * 64 + l], acc[tt], 0, 0, 0);
    }
    const int e = s8 * 16 + c;
    #pragma unroll
    for (int r4 = 0; r4 < 4; ++r4) {
      int fr = rt * 16 + q * 4 + r4;          // D row = (l>>4)*4 + reg
      ushort4 o = make_ushort4(f2bf(acc[0][r4]), f2bf(acc[1][r4]),
                               f2bf(acc[2][r4]), f2bf(acc[3][r4]));
      *reinterpret_cast<ushort4*>(P16 + ((size_t)fr * 128 + e) * 4) = o;
    }
  }
}

// ---------------------------------------------------------------------------
// Kernel 2: PURE recurrent LSTM (identical to round 15's).
// ---------------------------------------------------------------------------
__global__ __launch_bounds__(512, 2) void lstm_kernel(
    const unsigned short* __restrict__ P16, const float* __restrict__ Whh,
    const float* __restrict__ h0, const float* __restrict__ c0,
    unsigned short* __restrict__ hst)
{
  __shared__ __align__(16) unsigned short hfrag[2][2048];  // 8 KB h, frag order
  __shared__ __align__(16) unsigned int lpad[19456];       // 76 KB placement pad

  const int bg  = blockIdx.x;
  const int tid = threadIdx.x;
  const int w   = tid >> 6;
  const int l   = tid & 63;
  const int c   = l & 15;
  const int q   = l >> 4;
  const int ew  = 16 * w + c;

  bf16x8 wh[4][4];
  #pragma unroll
  for (int tt = 0; tt < 4; ++tt) {
    const int gcol = tt * HH + ew;
    #pragma unroll
    for (int kt = 0; kt < 4; ++kt)
      wh[tt][kt] = load8_bf(Whh + (size_t)gcol * HH + kt * 32 + q * 8);
  }

  float cst[2];
  #pragma unroll
  for (int r = 0; r < 2; ++r)
    cst[r] = c0[(size_t)(bg * NB + q * 2 + r) * HH + ew];

  {
    int4 z = {0, 0, 0, 0};
    reinterpret_cast<int4*>(hfrag)[tid] = z;
  }
  for (int i = tid; i < 19456; i += 512) lpad[i] = 0u;
  unsigned int keep = lpad[tid];
  asm volatile("" :: "v"(keep));
  __syncthreads();

  for (int idx = tid; idx < NB * HH; idx += 512) {
    int lb = idx >> 7, k = idx & 127;
    int row = ((lb >> 1) << 2) + (lb & 1);
    hfrag[0][frag_idx(row, k)] = f2bf(h0[(size_t)(bg * NB + lb) * HH + k]);
  }

  const unsigned short* pb0 =
      P16 + (size_t)(bg * NB + q * 2 + 0) * (TT * 512) + ew * 4;
  const unsigned short* pb1 =
      P16 + (size_t)(bg * NB + q * 2 + 1) * (TT * 512) + ew * 4;
  ushort4 pA[2], pB[2];
  pA[0] = *reinterpret_cast<const ushort4*>(pb0);
  pA[1] = *reinterpret_cast<const ushort4*>(pb1);
  pB[0] = *reinterpret_cast<const ushort4*>(pb0 + 512);
  pB[1] = *reinterpret_cast<const ushort4*>(pb1 + 512);

  unsigned short hp[2] = {0, 0};
  unsigned short* hb0 = hst + (size_t)(bg * NB + q * 2 + 0) * TT * HH + ew;
  unsigned short* hb1 = hst + (size_t)(bg * NB + q * 2 + 1) * TT * HH + ew;

  const int hw_off = frag_idx(q * 4, ew);
  __syncthreads();

  auto step = [&](int s, ushort4 (&pcur)[2]) {
    const int rb = s & 1;

    if (s >= 1 && s <= TT) {
      hb0[(size_t)(s - 1) * HH] = hp[0];
      hb1[(size_t)(s - 1) * HH] = hp[1];
    }

    if (s < TT) {
      bf16x8 ha[4];
      const bf16x8* hr = reinterpret_cast<const bf16x8*>(&hfrag[rb][0]) + l;
      #pragma unroll
      for (int kt = 0; kt < 4; ++kt) ha[kt] = hr[kt * 64];

      f32x4 acc[4];
      #pragma unroll
      for (int tt = 0; tt < 4; ++tt) {
        f32x4 z = {0.f, 0.f, 0.f, 0.f};
        acc[tt] = z;
      }
      acc[0][0] = bf2f(pcur[0].x); acc[1][0] = bf2f(pcur[0].y);
      acc[2][0] = bf2f(pcur[0].z); acc[3][0] = bf2f(pcur[0].w);
      acc[0][1] = bf2f(pcur[1].x); acc[1][1] = bf2f(pcur[1].y);
      acc[2][1] = bf2f(pcur[1].z); acc[3][1] = bf2f(pcur[1].w);

      if (s + 2 < TT) {
        pcur[0] = *reinterpret_cast<const ushort4*>(pb0 + (size_t)(s + 2) * 512);
        pcur[1] = *reinterpret_cast<const ushort4*>(pb1 + (size_t)(s + 2) * 512);
      }

      #pragma unroll
      for (int kt = 0; kt < 4; ++kt) {
        #pragma unroll
        for (int tt = 0; tt < 4; ++tt)
          acc[tt] = __builtin_amdgcn_mfma_f32_16x16x32_bf16(ha[kt], wh[tt][kt], acc[tt], 0, 0, 0);
      }

      unsigned short* hwp = &hfrag[rb ^ 1][hw_off];
      #pragma unroll
      for (int r = 0; r < 2; ++r) {
        float ai  = __builtin_amdgcn_exp2f(acc[0][r] * -1.44269504f);
        float bgg = __builtin_amdgcn_exp2f(acc[2][r] * -2.88539008f);
        float af  = __builtin_amdgcn_exp2f(acc[1][r] * -1.44269504f);
        float ao  = __builtin_amdgcn_exp2f(acc[3][r] * -1.44269504f);
        float sitg = (1.0f - bgg) *
                     __builtin_amdgcn_rcpf((1.0f + ai) * (1.0f + bgg));
        float sf = __builtin_amdgcn_rcpf(1.0f + af);
        cst[r] = __fmaf_rn(sf, cst[r], sitg);
        float cc = __builtin_amdgcn_fmed3f(cst[r], -30.0f, 30.0f);
        float ec = __builtin_amdgcn_exp2f(cc * -2.88539008f);
        float hv = (1.0f - ec) *
                   __builtin_amdgcn_rcpf((1.0f + ao) * (1.0f + ec));
        unsigned short hu = f2bf(hv);
        hwp[r * 8] = hu;
        hp[r] = hu;
      }
    }
    lds_barrier();
  };

  for (int s = 0; s < TT + 2; s += 2) {
    step(s, pA);
    step(s + 1, pB);
  }
}

// ---------------------------------------------------------------------------
// Kernel 3: fused emissions + Viterbi + backtrace, BARRIER-FREE (one wave per
// block = self-coherent through LDS; compiler inserts lgkmcnt waits).
// Per 16-t tile: 4 MFMA -> ering (dbuf) -> er[16] regs -> 16 DP steps where
// the 12 trellis values are gathered via __shfl (no LDS round-trip).
// Backtrace: bp rows chunk-loaded into lane registers, readlane chain.
// ---------------------------------------------------------------------------
__global__ __launch_bounds__(64) void vit_kernel(
    const unsigned short* __restrict__ hst, const float* __restrict__ Wtag,
    const float* __restrict__ btag, const float* __restrict__ trans,
    float* __restrict__ out)
{
  __shared__ __align__(16) float ering[2][16 * 16];
  __shared__ unsigned char bp[TT * KK];          // 6 KB backpointers
  __shared__ unsigned char path[TT];

  const int b = blockIdx.x, tid = threadIdx.x;   // 64 threads = 1 wave
  const int c = tid & 15, q = tid >> 4;
  const int j = tid;                             // DP tag lane (j<12 active)

  // trans column j in registers: trl_r[i] = trans[i][j]
  float trl_r[KK];
  #pragma unroll
  for (int i = 0; i < KK; ++i)
    trl_r[i] = (j < KK) ? trans[i * KK + j] : 0.f;

  // emission weight fragments (col = c; zero for c >= 12)
  bf16x8 we[4];
  #pragma unroll
  for (int kt = 0; kt < 4; ++kt) {
    #pragma unroll
    for (int i = 0; i < 8; ++i) we[kt][i] = 0;
  }
  float bt = 0.f;
  if (c < KK) {
    #pragma unroll
    for (int kt = 0; kt < 4; ++kt)
      we[kt] = load8_bf(Wtag + (size_t)c * HH + kt * 32 + q * 8);
    bt = btag[c];
  }
  const unsigned short* hb = hst + (size_t)b * TT * HH;

  // prologue: A-frags for tile 0 (rows t = c)
  bf16x8 ha[4];
  #pragma unroll
  for (int kt = 0; kt < 4; ++kt)
    ha[kt] = *reinterpret_cast<const bf16x8*>(
        hb + (size_t)c * HH + kt * 32 + q * 8);

  float v = 0.f;   // trellis value for tag j

  for (int tb = 0; tb < TT; tb += 16) {
    const int par = (tb >> 4) & 1;

    // emissions for this tile
    f32x4 accE = {0.f, 0.f, 0.f, 0.f};
    #pragma unroll
    for (int kt = 0; kt < 4; ++kt)
      accE = __builtin_amdgcn_mfma_f32_16x16x32_bf16(ha[kt], we[kt], accE, 0, 0, 0);
    #pragma unroll
    for (int r = 0; r < 4; ++r)
      ering[par][(q * 4 + r) * 16 + c] = accE[r] + bt;

    // prefetch next tile's A-frags (stays in flight under the DP, no barriers)
    if (tb + 16 < TT) {
      #pragma unroll
      for (int kt = 0; kt < 4; ++kt)
        ha[kt] = *reinterpret_cast<const bf16x8*>(
            hb + (size_t)(tb + 16 + c) * HH + kt * 32 + q * 8);
    }

    // this tile's E column for tag j -> registers
    float er[16];
    #pragma unroll
    for (int i = 0; i < 16; ++i) er[i] = ering[par][i * 16 + (j & 15)];

    // 16 DP steps, barrier-free
    #pragma unroll
    for (int i = 0; i < 16; ++i) {
      const int t = tb + i;
      float vv[KK];
      #pragma unroll
      for (int i2 = 0; i2 < KK; ++i2) vv[i2] = __shfl(v, i2);
      if (t == 0) {
        v = er[0];
      } else {
        float cand[KK];
        #pragma unroll
        for (int i2 = 0; i2 < KK; ++i2) cand[i2] = vv[i2] + trl_r[i2];
        float g0 = fmaxf(fmaxf(cand[0], cand[1]), cand[2]);
        float g1 = fmaxf(fmaxf(cand[3], cand[4]), cand[5]);
        float g2 = fmaxf(fmaxf(cand[6], cand[7]), cand[8]);
        float g3 = fmaxf(fmaxf(cand[9], cand[10]), cand[11]);
        float best = fmaxf(fmaxf(g0, g1), fmaxf(g2, g3));
        int bi = 11;
        #pragma unroll
        for (int k = 10; k >= 0; --k) bi = (cand[k] == best) ? k : bi;  // first-max
        v = er[i] + best;
        if (j < KK) bp[t * KK + j] = (unsigned char)bi;
      }
    }
  }

  // ---- score + argmax (computed uniformly in all lanes via shfl) ----
  float vv[KK];
  #pragma unroll
  for (int i2 = 0; i2 < KK; ++i2) vv[i2] = __shfl(v, i2);
  float best = vv[0];
  int tag = 0;
  #pragma unroll
  for (int i2 = 1; i2 < KK; ++i2)
    if (vv[i2] > best) { best = vv[i2]; tag = i2; }   // first-max
  if (tid == 0) {
    out[b] = best;
    path[TT - 1] = (unsigned char)tag;
  }

  // ---- backtrace: 64-row chunks in registers, readlane chain ----
  for (int tb = TT - 64; tb >= 0; tb -= 64) {
    const unsigned* bpw =
        reinterpret_cast<const unsigned*>(bp + (size_t)(tb + tid) * KK);
    unsigned r0 = bpw[0], r1 = bpw[1], r2 = bpw[2];
    #pragma unroll
    for (int i = 63; i >= 0; --i) {
      const int t = tb + i;
      if (t >= 1) {
        unsigned d0 = __shfl(r0, i), d1 = __shfl(r1, i), d2 = __shfl(r2, i);
        unsigned d = (tag < 4) ? d0 : ((tag < 8) ? d1 : d2);
        tag = (int)((d >> ((tag & 3) * 8)) & 0xffu);
        if (tid == 0) path[t - 1] = (unsigned char)tag;
      }
    }
  }

  // ---- coalesced path output ----
  #pragma unroll
  for (int i = 0; i < 8; ++i)
    out[BB + (size_t)b * TT + tid + i * 64] = (float)path[tid + i * 64];
}

// ---------------------------------------------------------------------------
extern "C" void kernel_launch(void* const* d_in, const int* in_sizes, int n_in,
                              void* d_out, int out_size, void* d_ws, size_t ws_size,
                              hipStream_t stream) {
  const int*   sent  = (const int*)d_in[0];
  const float* h0    = (const float*)d_in[1];
  const float* c0    = (const float*)d_in[2];
  const float* embed = (const float*)d_in[3];
  const float* Wih   = (const float*)d_in[4];
  const float* Whh   = (const float*)d_in[5];
  const float* bih   = (const float*)d_in[6];
  const float* bhh   = (const float*)d_in[7];
  const float* Wtag  = (const float*)d_in[8];
  const float* btag  = (const float*)d_in[9];
  const float* trans = (const float*)d_in[10];
  float* out = (float*)d_out;

  // workspace: ebf 12.9MB | wbf 128KB | P16 64MB | hst 16MB   (~93MB)
  unsigned short* ebf = (unsigned short*)d_ws;
  unsigned short* wbf = ebf + (size_t)VV * 128;
  unsigned short* P16 = wbf + 8192 * 8;
  unsigned short* hst = P16 + (size_t)BB * TT * 512;

  prep_kernel<<<NPRE + 32, 256, 0, stream>>>(embed, Wih, bih, bhh, ebf, wbf);
  pregates_kernel<<<(BB * TT / 16) / 4, 256, 0, stream>>>(sent, ebf, wbf, P16);
  lstm_kernel<<<NBLK, 512, 0, stream>>>(P16, Whh, h0, c0, hst);
  vit_kernel<<<BB, 64, 0, stream>>>(hst, Wtag, btag, trans, out);
}